// Round 2
// baseline (429.418 us; speedup 1.0000x reference)
//
#include <hip/hip_runtime.h>
#include <hip/hip_bf16.h>

typedef unsigned int u32;
typedef unsigned short u16;
typedef __attribute__((ext_vector_type(8))) short short8;
typedef __attribute__((ext_vector_type(4))) float f32x4;

#define EPSV 1e-5f
#define MAXN (1.0f - 1e-5f)
#define THETA 0.17f
#define CAP 512

__device__ __forceinline__ u16 f2bf(float f) {
    union { float f; u32 u; } v; v.f = f;
    u32 u = v.u;
    u32 r = (u + 0x7fffu + ((u >> 16) & 1u)) >> 16;
    return (u16)r;
}
__device__ __forceinline__ float bf2f(u16 h) {
    union { u32 u; float f; } v; v.u = ((u32)h) << 16;
    return v.f;
}

// ---------------- memory bank: project + bf16 + y2 (also zeros cnt) ----------------
__global__ __launch_bounds__(256) void k_mem(const float* __restrict__ mem,
                                             u16* __restrict__ mbf,
                                             float* __restrict__ y2m,
                                             u32* __restrict__ cnt) {
    int zi = blockIdx.x * 256 + threadIdx.x;
    if (zi < 2048) cnt[zi] = 0;
    const int row = blockIdx.x * 4 + (threadIdx.x >> 6);
    const int lane = threadIdx.x & 63;
    const float4* p = (const float4*)(mem + (size_t)row * 256);
    float4 v = p[lane];
    float ss = v.x * v.x + v.y * v.y + v.z * v.z + v.w * v.w;
#pragma unroll
    for (int off = 32; off; off >>= 1) ss += __shfl_xor(ss, off);
    float norm = sqrtf(ss);
    float scale = (norm > MAXN) ? MAXN / fmaxf(norm, EPSV) : 1.0f;
    ushort4 u;
    u.x = f2bf(v.x * scale); u.y = f2bf(v.y * scale);
    u.z = f2bf(v.z * scale); u.w = f2bf(v.w * scale);
    *(ushort4*)&mbf[(size_t)row * 256 + lane * 4] = u;
    if (lane == 0) y2m[row] = ss * scale * scale;
}

// ---------------- f32 -> bf16 convert (x4 per thread) ----------------
__global__ __launch_bounds__(256) void k_conv4(const float* __restrict__ in,
                                               u16* __restrict__ out, int n4) {
    int i = blockIdx.x * 256 + threadIdx.x;
    if (i < n4) {
        float4 v = ((const float4*)in)[i];
        ushort4 u; u.x = f2bf(v.x); u.y = f2bf(v.y); u.z = f2bf(v.z); u.w = f2bf(v.w);
        ((ushort4*)out)[i] = u;
    }
}

// ---------------- transpose + convert: out[n*K+k] = bf16(in[k*N+n]) ----------------
__global__ __launch_bounds__(256) void k_tr(const float* __restrict__ in,
                                            u16* __restrict__ out, int K, int N) {
    int idx = blockIdx.x * 256 + threadIdx.x;
    if (idx < K * N) {
        int nn = idx / K;
        int kk = idx - nn * K;
        out[idx] = f2bf(in[(size_t)kk * N + nn]);
    }
}

// ---------------- GEMM1 (2048x1024x256) + bias + LayerNorm + GELU -> qg bf16 ----------------
__global__ __launch_bounds__(256) void k_g1(const u16* __restrict__ hb,
                                            const u16* __restrict__ w1t,
                                            const float* __restrict__ b1,
                                            const float* __restrict__ lng,
                                            const float* __restrict__ lnb,
                                            u16* __restrict__ qg) {
    __shared__ float sm[16 * 260];
    const int t = threadIdx.x;
    const int w = t >> 6, lane = t & 63;
    const int l16 = lane & 15, kq = (lane >> 4) * 8, rbase = (lane >> 4) * 4;
    const int q0 = blockIdx.x * 16;
    f32x4 zero = {0.f, 0.f, 0.f, 0.f};
    f32x4 acc[4] = {zero, zero, zero, zero};
    const u16* ap = hb + (size_t)(q0 + l16) * 1024 + kq;
    for (int k0 = 0; k0 < 1024; k0 += 32) {
        short8 av = *(const short8*)(ap + k0);
#pragma unroll
        for (int ct = 0; ct < 4; ++ct) {
            int n = w * 64 + ct * 16 + l16;
            short8 bv = *(const short8*)&w1t[(size_t)n * 1024 + k0 + kq];
            acc[ct] = __builtin_amdgcn_mfma_f32_16x16x32_bf16(av, bv, acc[ct], 0, 0, 0);
        }
    }
#pragma unroll
    for (int ct = 0; ct < 4; ++ct) {
        int n = w * 64 + ct * 16 + l16;
        float bias = b1[n];
#pragma unroll
        for (int r = 0; r < 4; ++r)
            sm[(rbase + r) * 260 + n] = acc[ct][r] + bias;
    }
    __syncthreads();
    const int row = t >> 4, sub = t & 15;
    float s1 = 0.f, s2 = 0.f;
#pragma unroll
    for (int i = 0; i < 16; ++i) {
        float v = sm[row * 260 + sub + 16 * i];
        s1 += v; s2 += v * v;
    }
#pragma unroll
    for (int off = 8; off; off >>= 1) {
        s1 += __shfl_xor(s1, off, 16);
        s2 += __shfl_xor(s2, off, 16);
    }
    float mu = s1 * (1.0f / 256.0f);
    float var = s2 * (1.0f / 256.0f) - mu * mu;
    float rstd = rsqrtf(var + EPSV);
#pragma unroll
    for (int i = 0; i < 16; ++i) {
        int cc = sub + 16 * i;
        float v = sm[row * 260 + cc];
        float xn = (v - mu) * rstd * lng[cc] + lnb[cc];
        float ge = 0.5f * xn * (1.0f + erff(xn * 0.7071067811865475f));
        qg[(size_t)(q0 + row) * 256 + cc] = f2bf(ge);
    }
}

// ---------------- GEMM2 (2048x256x256) + bias + Poincare project -> qb bf16, x2 ----------------
__global__ __launch_bounds__(256) void k_g2(const u16* __restrict__ qg,
                                            const u16* __restrict__ w2t,
                                            const float* __restrict__ b2,
                                            u16* __restrict__ qbb,
                                            float* __restrict__ x2q) {
    __shared__ float sm[16 * 260];
    const int t = threadIdx.x;
    const int w = t >> 6, lane = t & 63;
    const int l16 = lane & 15, kq = (lane >> 4) * 8, rbase = (lane >> 4) * 4;
    const int q0 = blockIdx.x * 16;
    f32x4 zero = {0.f, 0.f, 0.f, 0.f};
    f32x4 acc[4] = {zero, zero, zero, zero};
    const u16* ap = qg + (size_t)(q0 + l16) * 256 + kq;
    for (int k0 = 0; k0 < 256; k0 += 32) {
        short8 av = *(const short8*)(ap + k0);
#pragma unroll
        for (int ct = 0; ct < 4; ++ct) {
            int n = w * 64 + ct * 16 + l16;
            short8 bv = *(const short8*)&w2t[(size_t)n * 256 + k0 + kq];
            acc[ct] = __builtin_amdgcn_mfma_f32_16x16x32_bf16(av, bv, acc[ct], 0, 0, 0);
        }
    }
#pragma unroll
    for (int ct = 0; ct < 4; ++ct) {
        int n = w * 64 + ct * 16 + l16;
        float bias = b2[n];
#pragma unroll
        for (int r = 0; r < 4; ++r)
            sm[(rbase + r) * 260 + n] = acc[ct][r] + bias;
    }
    __syncthreads();
    const int row = t >> 4, sub = t & 15;
    float s2 = 0.f;
#pragma unroll
    for (int i = 0; i < 16; ++i) {
        float v = sm[row * 260 + sub + 16 * i];
        s2 += v * v;
    }
#pragma unroll
    for (int off = 8; off; off >>= 1) s2 += __shfl_xor(s2, off, 16);
    float norm = sqrtf(s2);
    float scale = (norm > MAXN) ? MAXN / fmaxf(norm, EPSV) : 1.0f;
    if (sub == 0) x2q[q0 + row] = s2 * scale * scale;
#pragma unroll
    for (int i = 0; i < 16; ++i) {
        int cc = sub + 16 * i;
        qbb[(size_t)(q0 + row) * 256 + cc] = f2bf(sm[row * 260 + cc] * scale);
    }
}

// ---------------- main: MFMA dot products, register-double-buffered B prefetch ----------------
// grid 1024: qt = (b>>3)&31 (64 queries), sl = (b&7)|((b>>8)<<3) (2048 mem rows)
#define QS_STRIDE 264
__global__ __launch_bounds__(256, 3) void k_dist(const u16* __restrict__ qb,
                                                 const u16* __restrict__ mbf,
                                                 u32* __restrict__ cnt,
                                                 uint2* __restrict__ cand) {
    __shared__ u16 qs[64 * QS_STRIDE];
    const int b = blockIdx.x;
    const int sl = (b & 7) | ((b >> 8) << 3);
    const int qt = (b >> 3) & 31;
    const int t = threadIdx.x;
    {
        const u16* src = qb + (size_t)qt * 64 * 256;
#pragma unroll
        for (int i = 0; i < 8; ++i) {
            int seg = i * 256 + t;
            int row = seg >> 5, s = (seg & 31) * 8;
            *(short8*)&qs[row * QS_STRIDE + s] = *(const short8*)&src[row * 256 + s];
        }
    }
    __syncthreads();
    const int w = t >> 6, lane = t & 63;
    const int l16 = lane & 15, kq = (lane >> 4) * 8, rbase = (lane >> 4) * 4;
    f32x4 zero = {0.f, 0.f, 0.f, 0.f};

    // flat B prefetch pointer: wave w's rows for g are sl*2048 + (g*4+w)*64
    // g -> g+1 advances by 256 rows = 65536 u16
    const u16* pf = mbf + (size_t)(sl * 2048 + w * 64) * 256 + (size_t)l16 * 256 + kq;
    short8 bv_a[4], bv_b[4];
#pragma unroll
    for (int ct = 0; ct < 4; ++ct) bv_a[ct] = *(const short8*)(pf + ct * 4096);
    pf += 32;

    const u16* aq_base = qs + l16 * QS_STRIDE + kq;

#pragma unroll 1
    for (int g = 0; g < 8; ++g) {
        const int mbase = sl * 2048 + (g * 4 + w) * 64;
        f32x4 acc[4][4];
#pragma unroll
        for (int i = 0; i < 4; ++i)
#pragma unroll
            for (int j = 0; j < 4; ++j) acc[i][j] = zero;
        const u16* aqp = aq_base;
#pragma unroll 1
        for (int kk = 0; kk < 4; ++kk) {
            // prefetch odd step B (k = kk*64+32)
#pragma unroll
            for (int ct = 0; ct < 4; ++ct) bv_b[ct] = *(const short8*)(pf + ct * 4096);
            pf += 32;
            if (kk == 3) pf += 65536 - 256;   // jump to next g's k=0
            // even step compute (k = kk*64) with bv_a
            {
                short8 av[4];
#pragma unroll
                for (int rt = 0; rt < 4; ++rt)
                    av[rt] = *(const short8*)(aqp + rt * 16 * QS_STRIDE);
#pragma unroll
                for (int rt = 0; rt < 4; ++rt)
#pragma unroll
                    for (int ct = 0; ct < 4; ++ct)
                        acc[rt][ct] = __builtin_amdgcn_mfma_f32_16x16x32_bf16(av[rt], bv_a[ct], acc[rt][ct], 0, 0, 0);
            }
            // prefetch next even step B (k = (kk+1)*64, or next g's k=0)
#pragma unroll
            for (int ct = 0; ct < 4; ++ct) bv_a[ct] = *(const short8*)(pf + ct * 4096);
            pf += 32;
            // odd step compute (k = kk*64+32) with bv_b
            {
                short8 av[4];
#pragma unroll
                for (int rt = 0; rt < 4; ++rt)
                    av[rt] = *(const short8*)(aqp + 32 + rt * 16 * QS_STRIDE);
#pragma unroll
                for (int rt = 0; rt < 4; ++rt)
#pragma unroll
                    for (int ct = 0; ct < 4; ++ct)
                        acc[rt][ct] = __builtin_amdgcn_mfma_f32_16x16x32_bf16(av[rt], bv_b[ct], acc[rt][ct], 0, 0, 0);
            }
            aqp += 64;
        }
        // epilogue: threshold + candidate append
#pragma unroll
        for (int rt = 0; rt < 4; ++rt)
#pragma unroll
            for (int ct = 0; ct < 4; ++ct)
#pragma unroll
                for (int r = 0; r < 4; ++r) {
                    float d = acc[rt][ct][r];
                    if (d > THETA) {
                        int q = qt * 64 + rt * 16 + rbase + r;
                        int m = mbase + ct * 16 + l16;
                        u32 pos = atomicAdd(&cnt[q], 1u);
                        if (pos < CAP) cand[(size_t)q * CAP + pos] = make_uint2((u32)m, __float_as_uint(d));
                    }
                }
    }
}

// ---------------- merge: exact top-16, softmax(-dist), weighted gather -> rb bf16 ----------------
__global__ __launch_bounds__(64, 4) void k_merge(const u32* __restrict__ cnt,
                                                 const uint2* __restrict__ cand,
                                                 const float* __restrict__ x2q,
                                                 const float* __restrict__ y2m,
                                                 const u16* __restrict__ mbf,
                                                 u16* __restrict__ rb) {
    const int q = blockIdx.x;
    const int lane = threadIdx.x;
    int n = (int)cnt[q]; if (n > CAP) n = CAP;
    const float x2 = x2q[q];
    const float dx = 1.0f - x2;
    float rv[8]; u32 mi[8];
#pragma unroll
    for (int j = 0; j < 8; ++j) {
        int idx = lane + 64 * j;
        rv[j] = 3.0e38f; mi[j] = 0;
        if (idx < n) {
            uint2 c = cand[(size_t)q * CAP + idx];
            float dot = __uint_as_float(c.y);
            float y2 = y2m[c.x];
            float sq = fmaxf(x2 + y2 - 2.0f * dot, 0.0f);
            float den = fmaxf(dx * (1.0f - y2), EPSV);
            rv[j] = sq / den;
            mi[j] = c.x;
        }
    }
    __shared__ float sdist[16];
    __shared__ u32 smi[16];
    __shared__ float swt[16];
    for (int k = 0; k < 16; ++k) {
        float lm = rv[0]; int ls = 0;
#pragma unroll
        for (int j = 1; j < 8; ++j) if (rv[j] < lm) { lm = rv[j]; ls = j; }
        unsigned long long key = (((unsigned long long)__float_as_uint(lm)) << 32) | (u32)(lane * 8 + ls);
#pragma unroll
        for (int off = 32; off; off >>= 1) {
            unsigned long long o = __shfl_xor(key, off);
            key = (o < key) ? o : key;
        }
        u32 sid = (u32)(key & 0xffffffffu);
        int wl = (int)(sid >> 3), wslot = (int)(sid & 7);
        if (lane == wl) {
            sdist[k] = rv[wslot];
            smi[k] = mi[wslot];
            rv[wslot] = 3.0e38f;
        }
    }
    __syncthreads();
    float rr = sdist[lane & 15];
    float arg = fmaxf(fmaf(2.0f, rr, 1.0f), 1.0f + EPSV);
    float dneg = -acoshf(arg);
    float mx = dneg;
#pragma unroll
    for (int off = 8; off; off >>= 1) mx = fmaxf(mx, __shfl_xor(mx, off, 16));
    float e = expf(dneg - mx);
    float ssum = e;
#pragma unroll
    for (int off = 8; off; off >>= 1) ssum += __shfl_xor(ssum, off, 16);
    if (lane < 16) swt[lane] = e / ssum;
    __syncthreads();
    float acc[4] = {0.f, 0.f, 0.f, 0.f};
    for (int k = 0; k < 16; ++k) {
        float wk = swt[k];
        const u16* mr = mbf + (size_t)smi[k] * 256;
#pragma unroll
        for (int j = 0; j < 4; ++j) acc[j] += wk * bf2f(mr[lane + 64 * j]);
    }
#pragma unroll
    for (int j = 0; j < 4; ++j) rb[(size_t)q * 256 + lane + 64 * j] = f2bf(acc[j]);
}

// ---------------- output: out = hidden + 0.1*(rb @ wp + bp) ----------------
__global__ __launch_bounds__(256) void k_out(const u16* __restrict__ rb,
                                             const u16* __restrict__ wpt,
                                             const float* __restrict__ bp,
                                             const float* __restrict__ hidden,
                                             float* __restrict__ out) {
    const int b = blockIdx.x;
    const int mt = b & 31, nt = b >> 5;
    const int t = threadIdx.x;
    const int w = t >> 6, lane = t & 63;
    const int l16 = lane & 15, kq = (lane >> 4) * 8, rbase = (lane >> 4) * 4;
    const int n = nt * 64 + w * 16 + l16;
    f32x4 zero = {0.f, 0.f, 0.f, 0.f};
    f32x4 acc[4] = {zero, zero, zero, zero};
    for (int k0 = 0; k0 < 256; k0 += 32) {
        short8 bv = *(const short8*)&wpt[(size_t)n * 256 + k0 + kq];
#pragma unroll
        for (int rt = 0; rt < 4; ++rt) {
            short8 av = *(const short8*)&rb[(size_t)(mt * 64 + rt * 16 + l16) * 256 + k0 + kq];
            acc[rt] = __builtin_amdgcn_mfma_f32_16x16x32_bf16(av, bv, acc[rt], 0, 0, 0);
        }
    }
    float bpn = bp[n];
#pragma unroll
    for (int rt = 0; rt < 4; ++rt)
#pragma unroll
        for (int r = 0; r < 4; ++r) {
            int m = mt * 64 + rt * 16 + rbase + r;
            out[(size_t)m * 1024 + n] = hidden[(size_t)m * 1024 + n] + 0.1f * (acc[rt][r] + bpn);
        }
}

extern "C" void kernel_launch(void* const* d_in, const int* in_sizes, int n_in,
                              void* d_out, int out_size, void* d_ws, size_t ws_size,
                              hipStream_t stream) {
    const float* hidden = (const float*)d_in[0];
    const float* memory = (const float*)d_in[1];
    const float* w1 = (const float*)d_in[2];
    const float* b1 = (const float*)d_in[3];
    const float* ln_g = (const float*)d_in[4];
    const float* ln_b = (const float*)d_in[5];
    const float* w2 = (const float*)d_in[6];
    const float* b2 = (const float*)d_in[7];
    const float* wp = (const float*)d_in[8];
    const float* bp = (const float*)d_in[9];
    float* out = (float*)d_out;
    char* ws = (char*)d_ws;

    u16* mbf  = (u16*)(ws);                       // 33554432
    float* y2m = (float*)(ws + 33554432);         // 262144
    u16* hb   = (u16*)(ws + 33816576);            // 4194304
    u16* w1t  = (u16*)(ws + 38010880);            // 524288
    u16* w2t  = (u16*)(ws + 38535168);            // 131072
    u16* wpt  = (u16*)(ws + 38666240);            // 524288
    u16* qg   = (u16*)(ws + 39190528);            // 1048576
    u16* qbb  = (u16*)(ws + 40239104);            // 1048576
    float* x2q = (float*)(ws + 41287680);         // 8192
    u32* cnt  = (u32*)(ws + 41295872);            // 8192
    uint2* cand = (uint2*)(ws + 41304064);        // 8388608
    u16* rb   = (u16*)(ws + 49692672);            // 1048576

    hipLaunchKernelGGL(k_mem, dim3(16384), dim3(256), 0, stream, memory, mbf, y2m, cnt);
    hipLaunchKernelGGL(k_conv4, dim3(2048), dim3(256), 0, stream, hidden, hb, 2048 * 1024 / 4);
    hipLaunchKernelGGL(k_tr, dim3(1024), dim3(256), 0, stream, w1, w1t, 1024, 256);
    hipLaunchKernelGGL(k_tr, dim3(256), dim3(256), 0, stream, w2, w2t, 256, 256);
    hipLaunchKernelGGL(k_tr, dim3(1024), dim3(256), 0, stream, wp, wpt, 256, 1024);
    hipLaunchKernelGGL(k_g1, dim3(128), dim3(256), 0, stream, hb, w1t, b1, ln_g, ln_b, qg);
    hipLaunchKernelGGL(k_g2, dim3(128), dim3(256), 0, stream, qg, w2t, b2, qbb, x2q);
    hipLaunchKernelGGL(k_dist, dim3(1024), dim3(256), 0, stream, qbb, mbf, cnt, cand);
    hipLaunchKernelGGL(k_merge, dim3(2048), dim3(64), 0, stream, cnt, cand, x2q, y2m, mbf, rb);
    hipLaunchKernelGGL(k_out, dim3(512), dim3(256), 0, stream, rb, wpt, bp, hidden, out);
}

// Round 3
// 356.759 us; speedup vs baseline: 1.2037x; 1.2037x over previous
//
#include <hip/hip_runtime.h>
#include <hip/hip_bf16.h>

typedef unsigned int u32;
typedef unsigned short u16;
typedef __attribute__((ext_vector_type(8))) short short8;
typedef __attribute__((ext_vector_type(4))) float f32x4;

#define EPSV 1e-5f
#define MAXN (1.0f - 1e-5f)
#define THETA 0.17f
#define CAP 512

__device__ __forceinline__ u16 f2bf(float f) {
    union { float f; u32 u; } v; v.f = f;
    u32 u = v.u;
    u32 r = (u + 0x7fffu + ((u >> 16) & 1u)) >> 16;
    return (u16)r;
}
__device__ __forceinline__ float bf2f(u16 h) {
    union { u32 u; float f; } v; v.u = ((u32)h) << 16;
    return v.f;
}

typedef __attribute__((address_space(1))) const unsigned char gbuf_t;
typedef __attribute__((address_space(3))) unsigned char lbuf_t;
__device__ __forceinline__ void gl2lds16(const void* g, void* l) {
    __builtin_amdgcn_global_load_lds((gbuf_t*)g, (lbuf_t*)l, 16, 0, 0);
}

// ---------------- memory bank: project + bf16 + y2 (also zeros cnt) ----------------
__global__ __launch_bounds__(256) void k_mem(const float* __restrict__ mem,
                                             u16* __restrict__ mbf,
                                             float* __restrict__ y2m,
                                             u32* __restrict__ cnt) {
    int zi = blockIdx.x * 256 + threadIdx.x;
    if (zi < 2048) cnt[zi] = 0;
    const int row = blockIdx.x * 4 + (threadIdx.x >> 6);
    const int lane = threadIdx.x & 63;
    const float4* p = (const float4*)(mem + (size_t)row * 256);
    float4 v = p[lane];
    float ss = v.x * v.x + v.y * v.y + v.z * v.z + v.w * v.w;
#pragma unroll
    for (int off = 32; off; off >>= 1) ss += __shfl_xor(ss, off);
    float norm = sqrtf(ss);
    float scale = (norm > MAXN) ? MAXN / fmaxf(norm, EPSV) : 1.0f;
    ushort4 u;
    u.x = f2bf(v.x * scale); u.y = f2bf(v.y * scale);
    u.z = f2bf(v.z * scale); u.w = f2bf(v.w * scale);
    *(ushort4*)&mbf[(size_t)row * 256 + lane * 4] = u;
    if (lane == 0) y2m[row] = ss * scale * scale;
}

// ---------------- fused prep: hidden->bf16, transpose w1/w2/wp ----------------
__global__ __launch_bounds__(256) void k_prep(const float* __restrict__ hidden, u16* __restrict__ hb,
                                              const float* __restrict__ w1, u16* __restrict__ w1t,
                                              const float* __restrict__ w2, u16* __restrict__ w2t,
                                              const float* __restrict__ wp, u16* __restrict__ wpt) {
    const int b = blockIdx.x, t = threadIdx.x;
    if (b < 2048) {                       // hidden f32 -> bf16, float4 per thread
        int i = b * 256 + t;
        float4 v = ((const float4*)hidden)[i];
        ushort4 u; u.x = f2bf(v.x); u.y = f2bf(v.y); u.z = f2bf(v.z); u.w = f2bf(v.w);
        ((ushort4*)hb)[i] = u;
    } else if (b < 3072) {                // w1t[n*1024+k] = w1[k*256+n]
        int idx = (b - 2048) * 256 + t;
        int nn = idx >> 10, kk = idx & 1023;
        w1t[idx] = f2bf(w1[(size_t)kk * 256 + nn]);
    } else if (b < 3328) {                // w2t[n*256+k] = w2[k*256+n]
        int idx = (b - 3072) * 256 + t;
        int nn = idx >> 8, kk = idx & 255;
        w2t[idx] = f2bf(w2[(size_t)kk * 256 + nn]);
    } else {                              // wpt[n*256+k] = wp[k*1024+n]
        int idx = (b - 3328) * 256 + t;
        int nn = idx >> 8, kk = idx & 255;
        wpt[idx] = f2bf(wp[(size_t)kk * 1024 + nn]);
    }
}

// ---------------- GEMM1 (2048x1024x256) + bias + LayerNorm + GELU -> qg bf16 ----------------
__global__ __launch_bounds__(256) void k_g1(const u16* __restrict__ hb,
                                            const u16* __restrict__ w1t,
                                            const float* __restrict__ b1,
                                            const float* __restrict__ lng,
                                            const float* __restrict__ lnb,
                                            u16* __restrict__ qg) {
    __shared__ float sm[16 * 260];
    const int t = threadIdx.x;
    const int w = t >> 6, lane = t & 63;
    const int l16 = lane & 15, kq = (lane >> 4) * 8, rbase = (lane >> 4) * 4;
    const int q0 = blockIdx.x * 16;
    f32x4 zero = {0.f, 0.f, 0.f, 0.f};
    f32x4 acc[4] = {zero, zero, zero, zero};
    const u16* ap = hb + (size_t)(q0 + l16) * 1024 + kq;
    for (int k0 = 0; k0 < 1024; k0 += 32) {
        short8 av = *(const short8*)(ap + k0);
#pragma unroll
        for (int ct = 0; ct < 4; ++ct) {
            int n = w * 64 + ct * 16 + l16;
            short8 bv = *(const short8*)&w1t[(size_t)n * 1024 + k0 + kq];
            acc[ct] = __builtin_amdgcn_mfma_f32_16x16x32_bf16(av, bv, acc[ct], 0, 0, 0);
        }
    }
#pragma unroll
    for (int ct = 0; ct < 4; ++ct) {
        int n = w * 64 + ct * 16 + l16;
        float bias = b1[n];
#pragma unroll
        for (int r = 0; r < 4; ++r)
            sm[(rbase + r) * 260 + n] = acc[ct][r] + bias;
    }
    __syncthreads();
    const int row = t >> 4, sub = t & 15;
    float s1 = 0.f, s2 = 0.f;
#pragma unroll
    for (int i = 0; i < 16; ++i) {
        float v = sm[row * 260 + sub + 16 * i];
        s1 += v; s2 += v * v;
    }
#pragma unroll
    for (int off = 8; off; off >>= 1) {
        s1 += __shfl_xor(s1, off, 16);
        s2 += __shfl_xor(s2, off, 16);
    }
    float mu = s1 * (1.0f / 256.0f);
    float var = s2 * (1.0f / 256.0f) - mu * mu;
    float rstd = rsqrtf(var + EPSV);
#pragma unroll
    for (int i = 0; i < 16; ++i) {
        int cc = sub + 16 * i;
        float v = sm[row * 260 + cc];
        float xn = (v - mu) * rstd * lng[cc] + lnb[cc];
        float ge = 0.5f * xn * (1.0f + erff(xn * 0.7071067811865475f));
        qg[(size_t)(q0 + row) * 256 + cc] = f2bf(ge);
    }
}

// ---------------- GEMM2 (2048x256x256) + bias + Poincare project -> qb bf16, x2 ----------------
__global__ __launch_bounds__(256) void k_g2(const u16* __restrict__ qg,
                                            const u16* __restrict__ w2t,
                                            const float* __restrict__ b2,
                                            u16* __restrict__ qbb,
                                            float* __restrict__ x2q) {
    __shared__ float sm[16 * 260];
    const int t = threadIdx.x;
    const int w = t >> 6, lane = t & 63;
    const int l16 = lane & 15, kq = (lane >> 4) * 8, rbase = (lane >> 4) * 4;
    const int q0 = blockIdx.x * 16;
    f32x4 zero = {0.f, 0.f, 0.f, 0.f};
    f32x4 acc[4] = {zero, zero, zero, zero};
    const u16* ap = qg + (size_t)(q0 + l16) * 256 + kq;
    for (int k0 = 0; k0 < 256; k0 += 32) {
        short8 av = *(const short8*)(ap + k0);
#pragma unroll
        for (int ct = 0; ct < 4; ++ct) {
            int n = w * 64 + ct * 16 + l16;
            short8 bv = *(const short8*)&w2t[(size_t)n * 256 + k0 + kq];
            acc[ct] = __builtin_amdgcn_mfma_f32_16x16x32_bf16(av, bv, acc[ct], 0, 0, 0);
        }
    }
#pragma unroll
    for (int ct = 0; ct < 4; ++ct) {
        int n = w * 64 + ct * 16 + l16;
        float bias = b2[n];
#pragma unroll
        for (int r = 0; r < 4; ++r)
            sm[(rbase + r) * 260 + n] = acc[ct][r] + bias;
    }
    __syncthreads();
    const int row = t >> 4, sub = t & 15;
    float s2 = 0.f;
#pragma unroll
    for (int i = 0; i < 16; ++i) {
        float v = sm[row * 260 + sub + 16 * i];
        s2 += v * v;
    }
#pragma unroll
    for (int off = 8; off; off >>= 1) s2 += __shfl_xor(s2, off, 16);
    float norm = sqrtf(s2);
    float scale = (norm > MAXN) ? MAXN / fmaxf(norm, EPSV) : 1.0f;
    if (sub == 0) x2q[q0 + row] = s2 * scale * scale;
#pragma unroll
    for (int i = 0; i < 16; ++i) {
        int cc = sub + 16 * i;
        qbb[(size_t)(q0 + row) * 256 + cc] = f2bf(sm[row * 260 + cc] * scale);
    }
}

// ---------------- main: m97-style tiled MFMA GEMM + threshold candidate collection ----
// 128x128 tile, BK=32, K=256. grid 8192: mt = b>>4 (512 m-tiles), qt = b&15 (16 q-tiles).
// LDS staged via global_load_lds (width 16) with XOR quarter-swizzle:
//   LDS slot (row r, quarter qd) holds global quarter qd ^ ((r>>1)&3)
// -> every ds_read_b128 fragment read is exactly 2-way bank-aliased (free, m136).
__global__ __launch_bounds__(256, 3) void k_dist(const u16* __restrict__ qb,
                                                 const u16* __restrict__ mbf,
                                                 u32* __restrict__ cnt,
                                                 uint2* __restrict__ cand) {
    __shared__ u16 smem[8192];            // As[128][32] @0, Bs[128][32] @4096
    u16* As = smem;
    u16* Bs = smem + 4096;
    const int b = blockIdx.x;
    const int mt = b >> 4, qt = b & 15;
    const int q0 = qt * 128, m0 = mt * 128;
    const int t = threadIdx.x;
    const int w = t >> 6, lane = t & 63;
    const int l16 = lane & 15, Q = lane >> 4, rbase = Q * 4;

    // staging: wave w, chunk j covers rows (w*2+j)*16 + lane/4, quarter lane&3
    const u16* gA[2]; const u16* gB[2];
    u16 *lA[2], *lB[2];
#pragma unroll
    for (int j = 0; j < 2; ++j) {
        int r = (w * 2 + j) * 16 + (lane >> 2);
        int qs = (lane & 3) ^ ((r >> 1) & 3);
        gA[j] = qb + (size_t)(q0 + r) * 256 + qs * 8;
        gB[j] = mbf + (size_t)(m0 + r) * 256 + qs * 8;
        lA[j] = As + (w * 2 + j) * 512;   // wave-uniform LDS base
        lB[j] = Bs + (w * 2 + j) * 512;
    }

    // compute-side swizzled LDS element offsets (constant across K-iters)
    const int wq = w & 1, wm = w >> 1;
    int aoff[4], boff[4];
#pragma unroll
    for (int i = 0; i < 4; ++i) {
        int R = wq * 64 + i * 16 + l16;
        aoff[i] = R * 32 + (Q ^ ((R >> 1) & 3)) * 8;
        int S = wm * 64 + i * 16 + l16;
        boff[i] = S * 32 + (Q ^ ((S >> 1) & 3)) * 8;
    }

    f32x4 zero = {0.f, 0.f, 0.f, 0.f};
    f32x4 acc[4][4];
#pragma unroll
    for (int i = 0; i < 4; ++i)
#pragma unroll
        for (int j = 0; j < 4; ++j) acc[i][j] = zero;

#pragma unroll 1
    for (int kt = 0; kt < 8; ++kt) {
        if (kt) __syncthreads();          // all waves done reading previous tile
        const int ko = kt * 32;
        gl2lds16(gA[0] + ko, lA[0]);
        gl2lds16(gA[1] + ko, lA[1]);
        gl2lds16(gB[0] + ko, lB[0]);
        gl2lds16(gB[1] + ko, lB[1]);
        __syncthreads();                  // compiler drains vmcnt(0) before barrier
        short8 av[4], bv[4];
#pragma unroll
        for (int i = 0; i < 4; ++i) av[i] = *(const short8*)(As + aoff[i]);
#pragma unroll
        for (int i = 0; i < 4; ++i) bv[i] = *(const short8*)(Bs + boff[i]);
#pragma unroll
        for (int rt = 0; rt < 4; ++rt)
#pragma unroll
            for (int ct = 0; ct < 4; ++ct)
                acc[rt][ct] = __builtin_amdgcn_mfma_f32_16x16x32_bf16(av[rt], bv[ct], acc[rt][ct], 0, 0, 0);
    }

    // epilogue: threshold + candidate append
#pragma unroll
    for (int rt = 0; rt < 4; ++rt)
#pragma unroll
        for (int ct = 0; ct < 4; ++ct)
#pragma unroll
            for (int r = 0; r < 4; ++r) {
                float d = acc[rt][ct][r];
                if (d > THETA) {
                    int q = q0 + wq * 64 + rt * 16 + rbase + r;
                    int m = m0 + wm * 64 + ct * 16 + l16;
                    u32 pos = atomicAdd(&cnt[q], 1u);
                    if (pos < CAP) cand[(size_t)q * CAP + pos] = make_uint2((u32)m, __float_as_uint(d));
                }
            }
}

// ---------------- merge: exact top-16, softmax(-dist), weighted gather -> rb bf16 ----------------
__global__ __launch_bounds__(64, 4) void k_merge(const u32* __restrict__ cnt,
                                                 const uint2* __restrict__ cand,
                                                 const float* __restrict__ x2q,
                                                 const float* __restrict__ y2m,
                                                 const u16* __restrict__ mbf,
                                                 u16* __restrict__ rb) {
    const int q = blockIdx.x;
    const int lane = threadIdx.x;
    int n = (int)cnt[q]; if (n > CAP) n = CAP;
    const float x2 = x2q[q];
    const float dx = 1.0f - x2;
    float rv[8]; u32 mi[8];
#pragma unroll
    for (int j = 0; j < 8; ++j) {
        int idx = lane + 64 * j;
        rv[j] = 3.0e38f; mi[j] = 0;
        if (idx < n) {
            uint2 c = cand[(size_t)q * CAP + idx];
            float dot = __uint_as_float(c.y);
            float y2 = y2m[c.x];
            float sq = fmaxf(x2 + y2 - 2.0f * dot, 0.0f);
            float den = fmaxf(dx * (1.0f - y2), EPSV);
            rv[j] = sq / den;
            mi[j] = c.x;
        }
    }
    __shared__ float sdist[16];
    __shared__ u32 smi[16];
    __shared__ float swt[16];
    for (int k = 0; k < 16; ++k) {
        float lm = rv[0]; int ls = 0;
#pragma unroll
        for (int j = 1; j < 8; ++j) if (rv[j] < lm) { lm = rv[j]; ls = j; }
        unsigned long long key = (((unsigned long long)__float_as_uint(lm)) << 32) | (u32)(lane * 8 + ls);
#pragma unroll
        for (int off = 32; off; off >>= 1) {
            unsigned long long o = __shfl_xor(key, off);
            key = (o < key) ? o : key;
        }
        u32 sid = (u32)(key & 0xffffffffu);
        int wl = (int)(sid >> 3), wslot = (int)(sid & 7);
        if (lane == wl) {
            sdist[k] = rv[wslot];
            smi[k] = mi[wslot];
            rv[wslot] = 3.0e38f;
        }
    }
    __syncthreads();
    float rr = sdist[lane & 15];
    float arg = fmaxf(fmaf(2.0f, rr, 1.0f), 1.0f + EPSV);
    float dneg = -acoshf(arg);
    float mx = dneg;
#pragma unroll
    for (int off = 8; off; off >>= 1) mx = fmaxf(mx, __shfl_xor(mx, off, 16));
    float e = expf(dneg - mx);
    float ssum = e;
#pragma unroll
    for (int off = 8; off; off >>= 1) ssum += __shfl_xor(ssum, off, 16);
    if (lane < 16) swt[lane] = e / ssum;
    __syncthreads();
    float acc[4] = {0.f, 0.f, 0.f, 0.f};
    for (int k = 0; k < 16; ++k) {
        float wk = swt[k];
        const u16* mr = mbf + (size_t)smi[k] * 256;
#pragma unroll
        for (int j = 0; j < 4; ++j) acc[j] += wk * bf2f(mr[lane + 64 * j]);
    }
#pragma unroll
    for (int j = 0; j < 4; ++j) rb[(size_t)q * 256 + lane + 64 * j] = f2bf(acc[j]);
}

// ---------------- output: out = hidden + 0.1*(rb @ wp + bp) ----------------
__global__ __launch_bounds__(256) void k_out(const u16* __restrict__ rb,
                                             const u16* __restrict__ wpt,
                                             const float* __restrict__ bp,
                                             const float* __restrict__ hidden,
                                             float* __restrict__ out) {
    const int b = blockIdx.x;
    const int mt = b & 31, nt = b >> 5;
    const int t = threadIdx.x;
    const int w = t >> 6, lane = t & 63;
    const int l16 = lane & 15, kq = (lane >> 4) * 8, rbase = (lane >> 4) * 4;
    const int n = nt * 64 + w * 16 + l16;
    f32x4 zero = {0.f, 0.f, 0.f, 0.f};
    f32x4 acc[4] = {zero, zero, zero, zero};
    for (int k0 = 0; k0 < 256; k0 += 32) {
        short8 bv = *(const short8*)&wpt[(size_t)n * 256 + k0 + kq];
#pragma unroll
        for (int rt = 0; rt < 4; ++rt) {
            short8 av = *(const short8*)&rb[(size_t)(mt * 64 + rt * 16 + l16) * 256 + k0 + kq];
            acc[rt] = __builtin_amdgcn_mfma_f32_16x16x32_bf16(av, bv, acc[rt], 0, 0, 0);
        }
    }
    float bpn = bp[n];
#pragma unroll
    for (int rt = 0; rt < 4; ++rt)
#pragma unroll
        for (int r = 0; r < 4; ++r) {
            int m = mt * 64 + rt * 16 + rbase + r;
            out[(size_t)m * 1024 + n] = hidden[(size_t)m * 1024 + n] + 0.1f * (acc[rt][r] + bpn);
        }
}

extern "C" void kernel_launch(void* const* d_in, const int* in_sizes, int n_in,
                              void* d_out, int out_size, void* d_ws, size_t ws_size,
                              hipStream_t stream) {
    const float* hidden = (const float*)d_in[0];
    const float* memory = (const float*)d_in[1];
    const float* w1 = (const float*)d_in[2];
    const float* b1 = (const float*)d_in[3];
    const float* ln_g = (const float*)d_in[4];
    const float* ln_b = (const float*)d_in[5];
    const float* w2 = (const float*)d_in[6];
    const float* b2 = (const float*)d_in[7];
    const float* wp = (const float*)d_in[8];
    const float* bp = (const float*)d_in[9];
    float* out = (float*)d_out;
    char* ws = (char*)d_ws;

    u16* mbf  = (u16*)(ws);                       // 33554432
    float* y2m = (float*)(ws + 33554432);         // 262144
    u16* hb   = (u16*)(ws + 33816576);            // 4194304
    u16* w1t  = (u16*)(ws + 38010880);            // 524288
    u16* w2t  = (u16*)(ws + 38535168);            // 131072
    u16* wpt  = (u16*)(ws + 38666240);            // 524288
    u16* qg   = (u16*)(ws + 39190528);            // 1048576
    u16* qbb  = (u16*)(ws + 40239104);            // 1048576
    float* x2q = (float*)(ws + 41287680);         // 8192
    u32* cnt  = (u32*)(ws + 41295872);            // 8192
    uint2* cand = (uint2*)(ws + 41304064);        // 8388608
    u16* rb   = (u16*)(ws + 49692672);            // 1048576

    hipLaunchKernelGGL(k_mem, dim3(16384), dim3(256), 0, stream, memory, mbf, y2m, cnt);
    hipLaunchKernelGGL(k_prep, dim3(4352), dim3(256), 0, stream, hidden, hb, w1, w1t, w2, w2t, wp, wpt);
    hipLaunchKernelGGL(k_g1, dim3(128), dim3(256), 0, stream, hb, w1t, b1, ln_g, ln_b, qg);
    hipLaunchKernelGGL(k_g2, dim3(128), dim3(256), 0, stream, qg, w2t, b2, qbb, x2q);
    hipLaunchKernelGGL(k_dist, dim3(8192), dim3(256), 0, stream, qbb, mbf, cnt, cand);
    hipLaunchKernelGGL(k_merge, dim3(2048), dim3(64), 0, stream, cnt, cand, x2q, y2m, mbf, rb);
    hipLaunchKernelGGL(k_out, dim3(512), dim3(256), 0, stream, rb, wpt, bp, hidden, out);
}

// Round 4
// 307.563 us; speedup vs baseline: 1.3962x; 1.1600x over previous
//
#include <hip/hip_runtime.h>
#include <hip/hip_bf16.h>

typedef unsigned int u32;
typedef unsigned short u16;
typedef __attribute__((ext_vector_type(8))) short short8;
typedef __attribute__((ext_vector_type(4))) float f32x4;

#define EPSV 1e-5f
#define MAXN (1.0f - 1e-5f)
#define THETA 0.17f
#define CAP 512

__device__ __forceinline__ u16 f2bf(float f) {
    union { float f; u32 u; } v; v.f = f;
    u32 u = v.u;
    u32 r = (u + 0x7fffu + ((u >> 16) & 1u)) >> 16;
    return (u16)r;
}
__device__ __forceinline__ float bf2f(u16 h) {
    union { u32 u; float f; } v; v.u = ((u32)h) << 16;
    return v.f;
}

typedef __attribute__((address_space(1))) const unsigned char gbuf_t;
typedef __attribute__((address_space(3))) unsigned char lbuf_t;
__device__ __forceinline__ void gl2lds16(const void* g, void* l) {
    __builtin_amdgcn_global_load_lds((gbuf_t*)g, (lbuf_t*)l, 16, 0, 0);
}

// ---------------- memory bank: project + bf16 + y2 (also zeros cnt) ----------------
__global__ __launch_bounds__(256) void k_mem(const float* __restrict__ mem,
                                             u16* __restrict__ mbf,
                                             float* __restrict__ y2m,
                                             u32* __restrict__ cnt) {
    int zi = blockIdx.x * 256 + threadIdx.x;
    if (zi < 2048) cnt[zi] = 0;
    const int row = blockIdx.x * 4 + (threadIdx.x >> 6);
    const int lane = threadIdx.x & 63;
    const float4* p = (const float4*)(mem + (size_t)row * 256);
    float4 v = p[lane];
    float ss = v.x * v.x + v.y * v.y + v.z * v.z + v.w * v.w;
#pragma unroll
    for (int off = 32; off; off >>= 1) ss += __shfl_xor(ss, off);
    float norm = sqrtf(ss);
    float scale = (norm > MAXN) ? MAXN / fmaxf(norm, EPSV) : 1.0f;
    ushort4 u;
    u.x = f2bf(v.x * scale); u.y = f2bf(v.y * scale);
    u.z = f2bf(v.z * scale); u.w = f2bf(v.w * scale);
    *(ushort4*)&mbf[(size_t)row * 256 + lane * 4] = u;
    if (lane == 0) y2m[row] = ss * scale * scale;
}

// ---------------- fused prep: hidden->bf16, transpose w1/w2/wp ----------------
__global__ __launch_bounds__(256) void k_prep(const float* __restrict__ hidden, u16* __restrict__ hb,
                                              const float* __restrict__ w1, u16* __restrict__ w1t,
                                              const float* __restrict__ w2, u16* __restrict__ w2t,
                                              const float* __restrict__ wp, u16* __restrict__ wpt) {
    const int b = blockIdx.x, t = threadIdx.x;
    if (b < 2048) {                       // hidden f32 -> bf16, float4 per thread
        int i = b * 256 + t;
        float4 v = ((const float4*)hidden)[i];
        ushort4 u; u.x = f2bf(v.x); u.y = f2bf(v.y); u.z = f2bf(v.z); u.w = f2bf(v.w);
        ((ushort4*)hb)[i] = u;
    } else if (b < 3072) {                // w1t[n*1024+k] = w1[k*256+n]
        int idx = (b - 2048) * 256 + t;
        int nn = idx >> 10, kk = idx & 1023;
        w1t[idx] = f2bf(w1[(size_t)kk * 256 + nn]);
    } else if (b < 3328) {                // w2t[n*256+k] = w2[k*256+n]
        int idx = (b - 3072) * 256 + t;
        int nn = idx >> 8, kk = idx & 255;
        w2t[idx] = f2bf(w2[(size_t)kk * 256 + nn]);
    } else {                              // wpt[n*256+k] = wp[k*1024+n]
        int idx = (b - 3328) * 256 + t;
        int nn = idx >> 8, kk = idx & 255;
        wpt[idx] = f2bf(wp[(size_t)kk * 1024 + nn]);
    }
}

// ---------------- GEMM1 (2048x1024x256) + bias + LayerNorm + GELU -> qg bf16 ----------------
__global__ __launch_bounds__(256) void k_g1(const u16* __restrict__ hb,
                                            const u16* __restrict__ w1t,
                                            const float* __restrict__ b1,
                                            const float* __restrict__ lng,
                                            const float* __restrict__ lnb,
                                            u16* __restrict__ qg) {
    __shared__ float sm[16 * 260];
    const int t = threadIdx.x;
    const int w = t >> 6, lane = t & 63;
    const int l16 = lane & 15, kq = (lane >> 4) * 8, rbase = (lane >> 4) * 4;
    const int q0 = blockIdx.x * 16;
    f32x4 zero = {0.f, 0.f, 0.f, 0.f};
    f32x4 acc[4] = {zero, zero, zero, zero};
    const u16* ap = hb + (size_t)(q0 + l16) * 1024 + kq;
    for (int k0 = 0; k0 < 1024; k0 += 32) {
        short8 av = *(const short8*)(ap + k0);
#pragma unroll
        for (int ct = 0; ct < 4; ++ct) {
            int n = w * 64 + ct * 16 + l16;
            short8 bv = *(const short8*)&w1t[(size_t)n * 1024 + k0 + kq];
            acc[ct] = __builtin_amdgcn_mfma_f32_16x16x32_bf16(av, bv, acc[ct], 0, 0, 0);
        }
    }
#pragma unroll
    for (int ct = 0; ct < 4; ++ct) {
        int n = w * 64 + ct * 16 + l16;
        float bias = b1[n];
#pragma unroll
        for (int r = 0; r < 4; ++r)
            sm[(rbase + r) * 260 + n] = acc[ct][r] + bias;
    }
    __syncthreads();
    const int row = t >> 4, sub = t & 15;
    float s1 = 0.f, s2 = 0.f;
#pragma unroll
    for (int i = 0; i < 16; ++i) {
        float v = sm[row * 260 + sub + 16 * i];
        s1 += v; s2 += v * v;
    }
#pragma unroll
    for (int off = 8; off; off >>= 1) {
        s1 += __shfl_xor(s1, off, 16);
        s2 += __shfl_xor(s2, off, 16);
    }
    float mu = s1 * (1.0f / 256.0f);
    float var = s2 * (1.0f / 256.0f) - mu * mu;
    float rstd = rsqrtf(var + EPSV);
#pragma unroll
    for (int i = 0; i < 16; ++i) {
        int cc = sub + 16 * i;
        float v = sm[row * 260 + cc];
        float xn = (v - mu) * rstd * lng[cc] + lnb[cc];
        float ge = 0.5f * xn * (1.0f + erff(xn * 0.7071067811865475f));
        qg[(size_t)(q0 + row) * 256 + cc] = f2bf(ge);
    }
}

// ---------------- GEMM2 (2048x256x256) + bias + Poincare project -> qb bf16, x2 ----------------
__global__ __launch_bounds__(256) void k_g2(const u16* __restrict__ qg,
                                            const u16* __restrict__ w2t,
                                            const float* __restrict__ b2,
                                            u16* __restrict__ qbb,
                                            float* __restrict__ x2q) {
    __shared__ float sm[16 * 260];
    const int t = threadIdx.x;
    const int w = t >> 6, lane = t & 63;
    const int l16 = lane & 15, kq = (lane >> 4) * 8, rbase = (lane >> 4) * 4;
    const int q0 = blockIdx.x * 16;
    f32x4 zero = {0.f, 0.f, 0.f, 0.f};
    f32x4 acc[4] = {zero, zero, zero, zero};
    const u16* ap = qg + (size_t)(q0 + l16) * 256 + kq;
    for (int k0 = 0; k0 < 256; k0 += 32) {
        short8 av = *(const short8*)(ap + k0);
#pragma unroll
        for (int ct = 0; ct < 4; ++ct) {
            int n = w * 64 + ct * 16 + l16;
            short8 bv = *(const short8*)&w2t[(size_t)n * 256 + k0 + kq];
            acc[ct] = __builtin_amdgcn_mfma_f32_16x16x32_bf16(av, bv, acc[ct], 0, 0, 0);
        }
    }
#pragma unroll
    for (int ct = 0; ct < 4; ++ct) {
        int n = w * 64 + ct * 16 + l16;
        float bias = b2[n];
#pragma unroll
        for (int r = 0; r < 4; ++r)
            sm[(rbase + r) * 260 + n] = acc[ct][r] + bias;
    }
    __syncthreads();
    const int row = t >> 4, sub = t & 15;
    float s2 = 0.f;
#pragma unroll
    for (int i = 0; i < 16; ++i) {
        float v = sm[row * 260 + sub + 16 * i];
        s2 += v * v;
    }
#pragma unroll
    for (int off = 8; off; off >>= 1) s2 += __shfl_xor(s2, off, 16);
    float norm = sqrtf(s2);
    float scale = (norm > MAXN) ? MAXN / fmaxf(norm, EPSV) : 1.0f;
    if (sub == 0) x2q[q0 + row] = s2 * scale * scale;
#pragma unroll
    for (int i = 0; i < 16; ++i) {
        int cc = sub + 16 * i;
        qbb[(size_t)(q0 + row) * 256 + cc] = f2bf(sm[row * 260 + cc] * scale);
    }
}

// ---------------- main: tiled MFMA GEMM + threshold candidate collection ----------------
// 128x128 tile, BK=64, K=256 (4 stages). XCD-clustered dispatch:
//   mt = ((b>>7)<<3)|(b&7), qt = (b>>3)&15  -> the 16 blocks sharing a B-tile are
//   consecutive in dispatch AND on the same XCD (b%8 const) -> B-tile HBM-fetched once.
// LDS: As[128][64] + Bs[128][64] (32 KB), XOR chunk-swizzle (chunk' = chunk ^ (row&7))
//   -> ds_read_b128 fragment reads are uniformly distributed over banks (optimal).
__global__ __launch_bounds__(256, 4) void k_dist(const u16* __restrict__ qb,
                                                 const u16* __restrict__ mbf,
                                                 u32* __restrict__ cnt,
                                                 uint2* __restrict__ cand) {
    __shared__ u16 smem[16384];           // As @0 (8192 u16), Bs @8192
    u16* As = smem;
    const int b = blockIdx.x;
    const int qt = (b >> 3) & 15;
    const int mt = ((b >> 7) << 3) | (b & 7);
    const int q0 = qt * 128, m0 = mt * 128;
    const int t = threadIdx.x;
    const int w = t >> 6, lane = t & 63;
    const int l16 = lane & 15, Q = lane >> 4, rbase = Q * 4;

    // staging: issue i = w*4+j covers rows [i*8, i*8+8), all 8 chunks (16B each)
    const u16* pA[4];
    u16* lA[4];
#pragma unroll
    for (int j = 0; j < 4; ++j) {
        int i = w * 4 + j;
        int r = i * 8 + (lane >> 3);
        int c = (lane & 7) ^ (r & 7);
        pA[j] = qb + (size_t)(q0 + r) * 256 + c * 8;
        lA[j] = As + i * 512;             // wave-uniform LDS base (64 slots * 8 u16)
    }
    const ptrdiff_t dB = (mbf + (size_t)m0 * 256) - (qb + (size_t)q0 * 256); // uniform

    // compute-side swizzled LDS offsets (u16 units); h=1 sub-step = offset ^ 32
    const int wq = w & 1, wm = w >> 1;
    int aoff[4], boff[4];
#pragma unroll
    for (int i = 0; i < 4; ++i) {
        int R = wq * 64 + i * 16 + l16;
        aoff[i] = R * 64 + ((Q ^ (R & 7)) * 8);
        int S = wm * 64 + i * 16 + l16;
        boff[i] = 8192 + S * 64 + ((Q ^ (S & 7)) * 8);
    }

    f32x4 zero = {0.f, 0.f, 0.f, 0.f};
    f32x4 acc[4][4];
#pragma unroll
    for (int i = 0; i < 4; ++i)
#pragma unroll
        for (int j = 0; j < 4; ++j) acc[i][j] = zero;

#pragma unroll 1
    for (int kt = 0; kt < 4; ++kt) {
        if (kt) __syncthreads();          // all waves done reading previous tile
#pragma unroll
        for (int j = 0; j < 4; ++j) {
            gl2lds16(pA[j], lA[j]);
            gl2lds16(pA[j] + dB, lA[j] + 8192);
        }
#pragma unroll
        for (int j = 0; j < 4; ++j) pA[j] += 64;
        __syncthreads();                  // drains DMA (vmcnt 0)
#pragma unroll
        for (int h = 0; h < 2; ++h) {
            const int hx = h * 32;
            short8 av[4], bv[4];
#pragma unroll
            for (int i = 0; i < 4; ++i) av[i] = *(const short8*)(As + (aoff[i] ^ hx));
#pragma unroll
            for (int i = 0; i < 4; ++i) bv[i] = *(const short8*)(As + (boff[i] ^ hx));
#pragma unroll
            for (int rt = 0; rt < 4; ++rt)
#pragma unroll
                for (int ct = 0; ct < 4; ++ct)
                    acc[rt][ct] = __builtin_amdgcn_mfma_f32_16x16x32_bf16(av[rt], bv[ct], acc[rt][ct], 0, 0, 0);
        }
    }

    // epilogue: threshold + candidate append
#pragma unroll
    for (int rt = 0; rt < 4; ++rt)
#pragma unroll
        for (int ct = 0; ct < 4; ++ct)
#pragma unroll
            for (int r = 0; r < 4; ++r) {
                float d = acc[rt][ct][r];
                if (d > THETA) {
                    int q = q0 + wq * 64 + rt * 16 + rbase + r;
                    int m = m0 + wm * 64 + ct * 16 + l16;
                    u32 pos = atomicAdd(&cnt[q], 1u);
                    if (pos < CAP) cand[(size_t)q * CAP + pos] = make_uint2((u32)m, __float_as_uint(d));
                }
            }
}

// ---------------- merge: exact top-16, softmax(-dist), weighted gather -> rb bf16 ----------------
__global__ __launch_bounds__(64, 4) void k_merge(const u32* __restrict__ cnt,
                                                 const uint2* __restrict__ cand,
                                                 const float* __restrict__ x2q,
                                                 const float* __restrict__ y2m,
                                                 const u16* __restrict__ mbf,
                                                 u16* __restrict__ rb) {
    const int q = blockIdx.x;
    const int lane = threadIdx.x;
    int n = (int)cnt[q]; if (n > CAP) n = CAP;
    const float x2 = x2q[q];
    const float dx = 1.0f - x2;
    float rv[8]; u32 mi[8];
#pragma unroll
    for (int j = 0; j < 8; ++j) {
        int idx = lane + 64 * j;
        rv[j] = 3.0e38f; mi[j] = 0;
        if (idx < n) {
            uint2 c = cand[(size_t)q * CAP + idx];
            float dot = __uint_as_float(c.y);
            float y2 = y2m[c.x];
            float sq = fmaxf(x2 + y2 - 2.0f * dot, 0.0f);
            float den = fmaxf(dx * (1.0f - y2), EPSV);
            rv[j] = sq / den;
            mi[j] = c.x;
        }
    }
    __shared__ float sdist[16];
    __shared__ u32 smi[16];
    __shared__ float swt[16];
    for (int k = 0; k < 16; ++k) {
        float lm = rv[0]; int ls = 0;
#pragma unroll
        for (int j = 1; j < 8; ++j) if (rv[j] < lm) { lm = rv[j]; ls = j; }
        unsigned long long key = (((unsigned long long)__float_as_uint(lm)) << 32) | (u32)(lane * 8 + ls);
#pragma unroll
        for (int off = 32; off; off >>= 1) {
            unsigned long long o = __shfl_xor(key, off);
            key = (o < key) ? o : key;
        }
        u32 sid = (u32)(key & 0xffffffffu);
        int wl = (int)(sid >> 3), wslot = (int)(sid & 7);
        if (lane == wl) {
            sdist[k] = rv[wslot];
            smi[k] = mi[wslot];
            rv[wslot] = 3.0e38f;
        }
    }
    __syncthreads();
    float rr = sdist[lane & 15];
    float arg = fmaxf(fmaf(2.0f, rr, 1.0f), 1.0f + EPSV);
    float dneg = -acoshf(arg);
    float mx = dneg;
#pragma unroll
    for (int off = 8; off; off >>= 1) mx = fmaxf(mx, __shfl_xor(mx, off, 16));
    float e = expf(dneg - mx);
    float ssum = e;
#pragma unroll
    for (int off = 8; off; off >>= 1) ssum += __shfl_xor(ssum, off, 16);
    if (lane < 16) swt[lane] = e / ssum;
    __syncthreads();
    float acc[4] = {0.f, 0.f, 0.f, 0.f};
    for (int k = 0; k < 16; ++k) {
        float wk = swt[k];
        const u16* mr = mbf + (size_t)smi[k] * 256;
#pragma unroll
        for (int j = 0; j < 4; ++j) acc[j] += wk * bf2f(mr[lane + 64 * j]);
    }
#pragma unroll
    for (int j = 0; j < 4; ++j) rb[(size_t)q * 256 + lane + 64 * j] = f2bf(acc[j]);
}

// ---------------- output: out = hidden + 0.1*(rb @ wp + bp) ----------------
__global__ __launch_bounds__(256) void k_out(const u16* __restrict__ rb,
                                             const u16* __restrict__ wpt,
                                             const float* __restrict__ bp,
                                             const float* __restrict__ hidden,
                                             float* __restrict__ out) {
    const int b = blockIdx.x;
    const int mt = b & 31, nt = b >> 5;
    const int t = threadIdx.x;
    const int w = t >> 6, lane = t & 63;
    const int l16 = lane & 15, kq = (lane >> 4) * 8, rbase = (lane >> 4) * 4;
    const int n = nt * 64 + w * 16 + l16;
    f32x4 zero = {0.f, 0.f, 0.f, 0.f};
    f32x4 acc[4] = {zero, zero, zero, zero};
    for (int k0 = 0; k0 < 256; k0 += 32) {
        short8 bv = *(const short8*)&wpt[(size_t)n * 256 + k0 + kq];
#pragma unroll
        for (int rt = 0; rt < 4; ++rt) {
            short8 av = *(const short8*)&rb[(size_t)(mt * 64 + rt * 16 + l16) * 256 + k0 + kq];
            acc[rt] = __builtin_amdgcn_mfma_f32_16x16x32_bf16(av, bv, acc[rt], 0, 0, 0);
        }
    }
    float bpn = bp[n];
#pragma unroll
    for (int rt = 0; rt < 4; ++rt)
#pragma unroll
        for (int r = 0; r < 4; ++r) {
            int m = mt * 64 + rt * 16 + rbase + r;
            out[(size_t)m * 1024 + n] = hidden[(size_t)m * 1024 + n] + 0.1f * (acc[rt][r] + bpn);
        }
}

extern "C" void kernel_launch(void* const* d_in, const int* in_sizes, int n_in,
                              void* d_out, int out_size, void* d_ws, size_t ws_size,
                              hipStream_t stream) {
    const float* hidden = (const float*)d_in[0];
    const float* memory = (const float*)d_in[1];
    const float* w1 = (const float*)d_in[2];
    const float* b1 = (const float*)d_in[3];
    const float* ln_g = (const float*)d_in[4];
    const float* ln_b = (const float*)d_in[5];
    const float* w2 = (const float*)d_in[6];
    const float* b2 = (const float*)d_in[7];
    const float* wp = (const float*)d_in[8];
    const float* bp = (const float*)d_in[9];
    float* out = (float*)d_out;
    char* ws = (char*)d_ws;

    u16* mbf  = (u16*)(ws);                       // 33554432
    float* y2m = (float*)(ws + 33554432);         // 262144
    u16* hb   = (u16*)(ws + 33816576);            // 4194304
    u16* w1t  = (u16*)(ws + 38010880);            // 524288
    u16* w2t  = (u16*)(ws + 38535168);            // 131072
    u16* wpt  = (u16*)(ws + 38666240);            // 524288
    u16* qg   = (u16*)(ws + 39190528);            // 1048576
    u16* qbb  = (u16*)(ws + 40239104);            // 1048576
    float* x2q = (float*)(ws + 41287680);         // 8192
    u32* cnt  = (u32*)(ws + 41295872);            // 8192
    uint2* cand = (uint2*)(ws + 41304064);        // 8388608
    u16* rb   = (u16*)(ws + 49692672);            // 1048576

    hipLaunchKernelGGL(k_mem, dim3(16384), dim3(256), 0, stream, memory, mbf, y2m, cnt);
    hipLaunchKernelGGL(k_prep, dim3(4352), dim3(256), 0, stream, hidden, hb, w1, w1t, w2, w2t, wp, wpt);
    hipLaunchKernelGGL(k_g1, dim3(128), dim3(256), 0, stream, hb, w1t, b1, ln_g, ln_b, qg);
    hipLaunchKernelGGL(k_g2, dim3(128), dim3(256), 0, stream, qg, w2t, b2, qbb, x2q);
    hipLaunchKernelGGL(k_dist, dim3(8192), dim3(256), 0, stream, qbb, mbf, cnt, cand);
    hipLaunchKernelGGL(k_merge, dim3(2048), dim3(64), 0, stream, cnt, cand, x2q, y2m, mbf, rb);
    hipLaunchKernelGGL(k_out, dim3(512), dim3(256), 0, stream, rb, wpt, bp, hidden, out);
}